// Round 1
// baseline (879.445 us; speedup 1.0000x reference)
//
#include <hip/hip_runtime.h>
#include <hip/hip_bf16.h>

#define SLOPE 0.2f

static __device__ __forceinline__ float waveReduceSum(float v) {
#pragma unroll
  for (int off = 32; off > 0; off >>= 1) v += __shfl_xor(v, off, 64);
  return v;
}
static __device__ __forceinline__ float waveReduceMax(float v) {
#pragma unroll
  for (int off = 32; off > 0; off >>= 1) v = fmaxf(v, __shfl_xor(v, off, 64));
  return v;
}

// ---------- CSR build ----------
__global__ void count_kernel(const int* __restrict__ ei, int E, int N, int* __restrict__ deg) {
  int j = blockIdx.x * blockDim.x + threadIdx.x;
  int Etot = E + N;
  if (j >= Etot) return;
  int d = (j < E) ? ei[E + j] : (j - E);
  atomicAdd(&deg[d], 1);
}

__global__ __launch_bounds__(1024) void scan_kernel(const int* __restrict__ deg, int N,
                                                    int* __restrict__ rowptr) {
  __shared__ int sums[1024];
  int tid = threadIdx.x;
  int chunk = (N + 1023) >> 10;
  int lo = tid * chunk;
  int hi = min(lo + chunk, N);
  int s = 0;
  for (int i = lo; i < hi; ++i) s += deg[i];
  sums[tid] = s;
  __syncthreads();
  for (int off = 1; off < 1024; off <<= 1) {
    int v = (tid >= off) ? sums[tid - off] : 0;
    __syncthreads();
    sums[tid] += v;
    __syncthreads();
  }
  int run = (tid == 0) ? 0 : sums[tid - 1];
  for (int i = lo; i < hi; ++i) { rowptr[i] = run; run += deg[i]; }
  if (hi == N) rowptr[N] = sums[1023];
}

__global__ void scatter_kernel(const int* __restrict__ ei, int E, int N,
                               const int* __restrict__ rowptr, int* __restrict__ cnt,
                               int* __restrict__ srcs, int* __restrict__ dsts) {
  int j = blockIdx.x * blockDim.x + threadIdx.x;
  int Etot = E + N;
  if (j >= Etot) return;
  int s, d;
  if (j < E) { s = ei[j]; d = ei[E + j]; } else { s = j - E; d = j - E; }
  int pos = rowptr[d] + atomicAdd(&cnt[d], 1);
  srcs[pos] = s;
  dsts[pos] = d;
}

// ---------- Layer 1: edge logits (C=256, rank-1 features => scalar inputs) ----------
__global__ __launch_bounds__(256) void l1_edge_kernel(
    const float* __restrict__ x, const int* __restrict__ srcs, const int* __restrict__ dsts,
    int Etot, const float* __restrict__ Wl1, const float* __restrict__ bl1,
    const float* __restrict__ Wr1, const float* __restrict__ br1,
    const float* __restrict__ att1, float* __restrict__ elog) {
  int gtid = blockIdx.x * blockDim.x + threadIdx.x;
  int wid = gtid >> 6;
  int lane = threadIdx.x & 63;
  int base = wid << 6;
  if (base >= Etot) return;
  int c0 = lane * 4;
  float4 wl = *(const float4*)(Wl1 + c0);
  float4 wr = *(const float4*)(Wr1 + c0);
  float4 ba = *(const float4*)(bl1 + c0);
  float4 bb = *(const float4*)(br1 + c0);
  float4 at = *(const float4*)(att1 + c0);
  float cb0 = ba.x + bb.x, cb1 = ba.y + bb.y, cb2 = ba.z + bb.z, cb3 = ba.w + bb.w;
  int idx = base + lane;
  float xs = 0.f, xd = 0.f;
  if (idx < Etot) { xs = x[srcs[idx]]; xd = x[dsts[idx]]; }
  int nedge = min(64, Etot - base);
  float my_e = 0.f;
  for (int t = 0; t < nedge; ++t) {
    float xst = __shfl(xs, t, 64);
    float xdt = __shfl(xd, t, 64);
    float t0 = fmaf(xst, wl.x, fmaf(xdt, wr.x, cb0)); t0 = fmaxf(t0, SLOPE * t0);
    float t1 = fmaf(xst, wl.y, fmaf(xdt, wr.y, cb1)); t1 = fmaxf(t1, SLOPE * t1);
    float t2 = fmaf(xst, wl.z, fmaf(xdt, wr.z, cb2)); t2 = fmaxf(t2, SLOPE * t2);
    float t3 = fmaf(xst, wl.w, fmaf(xdt, wr.w, cb3)); t3 = fmaxf(t3, SLOPE * t3);
    float p = fmaf(t0, at.x, fmaf(t1, at.y, fmaf(t2, at.z, t3 * at.w)));
    p = waveReduceSum(p);
    if (lane == t) my_e = p;
  }
  if (idx < Etot) elog[idx] = my_e;
}

// ---------- Layer 1: per-dst softmax + scalar aggregation -> S1 ----------
__global__ __launch_bounds__(256) void l1_agg_kernel(
    const float* __restrict__ x, const float* __restrict__ elog,
    const int* __restrict__ srcs, const int* __restrict__ rowptr,
    int N, float* __restrict__ S1) {
  int wid = (blockIdx.x * blockDim.x + threadIdx.x) >> 6;
  int lane = threadIdx.x & 63;
  if (wid >= N) return;
  int base = rowptr[wid], end = rowptr[wid + 1];
  float m = -INFINITY;
  for (int k = base + lane; k < end; k += 64) m = fmaxf(m, elog[k]);
  m = waveReduceMax(m);
  float ps = 0.f, vs = 0.f;
  for (int k = base + lane; k < end; k += 64) {
    float p = __expf(elog[k] - m);
    ps += p;
    vs = fmaf(p, x[srcs[k]], vs);
  }
  ps = waveReduceSum(ps);
  vs = waveReduceSum(vs);
  if (lane == 0) S1[wid] = vs / ps;
}

// ---------- Layer 2 transform: h(S1) on the fly, GEMM 256->128 for Wl2 and Wr2 ----------
__global__ __launch_bounds__(512) void l2_transform_kernel(
    const float* __restrict__ S1,
    const float* __restrict__ Wl1, const float* __restrict__ bl1,
    const float* __restrict__ bias1, const float* __restrict__ prelu_w,
    const float* __restrict__ Wl2, const float* __restrict__ bl2,
    const float* __restrict__ Wr2, const float* __restrict__ br2,
    int N, float* __restrict__ xl2, float* __restrict__ xr2) {
  const int R = 16;
  __shared__ float hs[R][256];
  int i0 = blockIdx.x * R;
  int tid = threadIdx.x;
  for (int idx = tid; idx < R * 256; idx += 512) {
    int r = idx >> 8, k = idx & 255;
    int i = i0 + r;
    float hv = 0.f;
    if (i < N) {
      float t = fmaf(Wl1[k], S1[i], bl1[k] + bias1[k]);
      hv = (t > 0.f) ? t : prelu_w[k] * t;
    }
    hs[r][k] = hv;
  }
  __syncthreads();
  int r = tid >> 5;
  int co0 = (tid & 31) * 4;
  int i = i0 + r;
  float al0 = 0.f, al1 = 0.f, al2 = 0.f, al3 = 0.f;
  float ar0 = 0.f, ar1 = 0.f, ar2 = 0.f, ar3 = 0.f;
  for (int k = 0; k < 256; k += 4) {
    float4 hv = *(const float4*)&hs[r][k];
#pragma unroll
    for (int kk = 0; kk < 4; ++kk) {
      float h = (kk == 0) ? hv.x : (kk == 1) ? hv.y : (kk == 2) ? hv.z : hv.w;
      float4 wl = *(const float4*)(Wl2 + (size_t)(k + kk) * 128 + co0);
      float4 wr = *(const float4*)(Wr2 + (size_t)(k + kk) * 128 + co0);
      al0 = fmaf(h, wl.x, al0); al1 = fmaf(h, wl.y, al1);
      al2 = fmaf(h, wl.z, al2); al3 = fmaf(h, wl.w, al3);
      ar0 = fmaf(h, wr.x, ar0); ar1 = fmaf(h, wr.y, ar1);
      ar2 = fmaf(h, wr.z, ar2); ar3 = fmaf(h, wr.w, ar3);
    }
  }
  if (i < N) {
    float4 b2 = *(const float4*)(bl2 + co0);
    float4 r2 = *(const float4*)(br2 + co0);
    float4 ol = make_float4(al0 + b2.x, al1 + b2.y, al2 + b2.z, al3 + b2.w);
    float4 orr = make_float4(ar0 + r2.x, ar1 + r2.y, ar2 + r2.z, ar3 + r2.w);
    *(float4*)(xl2 + (size_t)i * 128 + co0) = ol;
    *(float4*)(xr2 + (size_t)i * 128 + co0) = orr;
  }
}

// ---------- Layer 2: edge logits (C=128) ----------
__global__ __launch_bounds__(256) void l2_edge_kernel(
    const float* __restrict__ xl2, const float* __restrict__ xr2,
    const int* __restrict__ srcs, const int* __restrict__ dsts, int Etot,
    const float* __restrict__ att2, float* __restrict__ elog) {
  int gtid = blockIdx.x * blockDim.x + threadIdx.x;
  int wid = gtid >> 6;
  int lane = threadIdx.x & 63;
  int base = wid << 6;
  if (base >= Etot) return;
  int c0 = lane * 2;
  float2 at = *(const float2*)(att2 + c0);
  int idx = base + lane;
  int sv = 0, dv = 0;
  if (idx < Etot) { sv = srcs[idx]; dv = dsts[idx]; }
  int nedge = min(64, Etot - base);
  float my_e = 0.f;
  for (int t = 0; t < nedge; ++t) {
    int s = __shfl(sv, t, 64);
    int d = __shfl(dv, t, 64);
    float2 a = *(const float2*)(xl2 + (size_t)s * 128 + c0);
    float2 b = *(const float2*)(xr2 + (size_t)d * 128 + c0);
    float v0 = a.x + b.x; v0 = fmaxf(v0, SLOPE * v0);
    float v1 = a.y + b.y; v1 = fmaxf(v1, SLOPE * v1);
    float p = fmaf(v0, at.x, v1 * at.y);
    p = waveReduceSum(p);
    if (lane == t) my_e = p;
  }
  if (idx < Etot) elog[idx] = my_e;
}

// ---------- Layer 2: per-dst softmax + row aggregation -> out ----------
__global__ __launch_bounds__(256) void l2_agg_kernel(
    const float* __restrict__ xl2, const float* __restrict__ elog,
    const int* __restrict__ srcs, const int* __restrict__ rowptr,
    const float* __restrict__ bias2, int N, float* __restrict__ out) {
  int wid = (blockIdx.x * blockDim.x + threadIdx.x) >> 6;
  int lane = threadIdx.x & 63;
  if (wid >= N) return;
  int base = rowptr[wid], end = rowptr[wid + 1];
  int c0 = lane * 2;
  float m = -INFINITY;
  for (int k = base + lane; k < end; k += 64) m = fmaxf(m, elog[k]);
  m = waveReduceMax(m);
  float ps = 0.f, a0 = 0.f, a1 = 0.f;
  for (int kb = base; kb < end; kb += 64) {
    int k = kb + lane;
    float p = 0.f; int sv = 0;
    if (k < end) { p = __expf(elog[k] - m); sv = srcs[k]; }
    ps += p;
    int lim = min(64, end - kb);
    for (int t = 0; t < lim; ++t) {
      float alpha = __shfl(p, t, 64);
      int s = __shfl(sv, t, 64);
      float2 row = *(const float2*)(xl2 + (size_t)s * 128 + c0);
      a0 = fmaf(alpha, row.x, a0);
      a1 = fmaf(alpha, row.y, a1);
    }
  }
  ps = waveReduceSum(ps);
  float inv = 1.f / ps;
  float2 bz = *(const float2*)(bias2 + c0);
  float2 res;
  res.x = fmaf(a0, inv, bz.x);
  res.y = fmaf(a1, inv, bz.y);
  *(float2*)(out + (size_t)wid * 128 + c0) = res;
}

extern "C" void kernel_launch(void* const* d_in, const int* in_sizes, int n_in,
                              void* d_out, int out_size, void* d_ws, size_t ws_size,
                              hipStream_t stream) {
  const float* x      = (const float*)d_in[0];
  const int*   ei     = (const int*)d_in[1];
  const float* Wl1    = (const float*)d_in[2];
  const float* bl1    = (const float*)d_in[3];
  const float* Wr1    = (const float*)d_in[4];
  const float* br1    = (const float*)d_in[5];
  const float* att1   = (const float*)d_in[6];
  const float* bias1  = (const float*)d_in[7];
  const float* prelu  = (const float*)d_in[8];
  const float* Wl2    = (const float*)d_in[9];
  const float* bl2    = (const float*)d_in[10];
  const float* Wr2    = (const float*)d_in[11];
  const float* br2    = (const float*)d_in[12];
  const float* att2   = (const float*)d_in[13];
  const float* bias2  = (const float*)d_in[14];
  float* out = (float*)d_out;

  int N = in_sizes[0];       // x is [N,1]
  int E = in_sizes[1] / 2;   // edge_index [2,E]
  int Etot = E + N;          // + self loops

  char* ws = (char*)d_ws;
  size_t off = 0;
  auto alloc = [&](size_t bytes) -> void* {
    void* p = ws + off;
    off = (off + bytes + 255) & ~(size_t)255;
    return p;
  };
  float* S1     = (float*)alloc((size_t)N * 4);
  float* elog   = (float*)alloc((size_t)Etot * 4);
  float* xl2    = (float*)alloc((size_t)N * 128 * 4);
  float* xr2    = (float*)alloc((size_t)N * 128 * 4);
  int*   deg    = (int*)alloc((size_t)N * 4);
  int*   cnt    = (int*)alloc((size_t)N * 4);
  int*   rowptr = (int*)alloc((size_t)(N + 1) * 4);
  int*   srcs   = (int*)alloc((size_t)Etot * 4);
  int*   dsts   = (int*)alloc((size_t)Etot * 4);
  (void)ws_size; (void)n_in; (void)out_size;

  hipMemsetAsync(deg, 0, (size_t)N * 4, stream);
  hipMemsetAsync(cnt, 0, (size_t)N * 4, stream);

  int gE = (Etot + 255) / 256;
  count_kernel<<<gE, 256, 0, stream>>>(ei, E, N, deg);
  scan_kernel<<<1, 1024, 0, stream>>>(deg, N, rowptr);
  scatter_kernel<<<gE, 256, 0, stream>>>(ei, E, N, rowptr, cnt, srcs, dsts);

  int gEdgeWave = (Etot + 255) / 256;  // 4 waves/block, 64 edges/wave
  l1_edge_kernel<<<gEdgeWave, 256, 0, stream>>>(x, srcs, dsts, Etot, Wl1, bl1, Wr1, br1, att1, elog);
  l1_agg_kernel<<<(N + 3) / 4, 256, 0, stream>>>(x, elog, srcs, rowptr, N, S1);

  l2_transform_kernel<<<(N + 15) / 16, 512, 0, stream>>>(S1, Wl1, bl1, bias1, prelu,
                                                         Wl2, bl2, Wr2, br2, N, xl2, xr2);
  l2_edge_kernel<<<gEdgeWave, 256, 0, stream>>>(xl2, xr2, srcs, dsts, Etot, att2, elog);
  l2_agg_kernel<<<(N + 3) / 4, 256, 0, stream>>>(xl2, elog, srcs, rowptr, bias2, N, out);
}

// Round 2
// 537.331 us; speedup vs baseline: 1.6367x; 1.6367x over previous
//
#include <hip/hip_runtime.h>
#include <hip/hip_bf16.h>

#define SLOPE 0.2f

typedef __attribute__((ext_vector_type(8))) short short8;
typedef __attribute__((ext_vector_type(4))) float f32x4;

static __device__ __forceinline__ float waveReduceSum(float v) {
#pragma unroll
  for (int off = 32; off > 0; off >>= 1) v += __shfl_xor(v, off, 64);
  return v;
}
static __device__ __forceinline__ float waveReduceMax(float v) {
#pragma unroll
  for (int off = 32; off > 0; off >>= 1) v = fmaxf(v, __shfl_xor(v, off, 64));
  return v;
}

// ---------- CSR build ----------
__global__ void count_kernel(const int* __restrict__ ei, int E, int N, int* __restrict__ deg) {
  int j = blockIdx.x * blockDim.x + threadIdx.x;
  int Etot = E + N;
  if (j >= Etot) return;
  int d = (j < E) ? ei[E + j] : (j - E);
  atomicAdd(&deg[d], 1);
}

__global__ __launch_bounds__(1024) void scan_kernel(const int* __restrict__ deg, int N,
                                                    int* __restrict__ rowptr) {
  __shared__ int sums[1024];
  int tid = threadIdx.x;
  int chunk = (N + 1023) >> 10;
  int lo = tid * chunk;
  int hi = min(lo + chunk, N);
  int s = 0;
  for (int i = lo; i < hi; ++i) s += deg[i];
  sums[tid] = s;
  __syncthreads();
  for (int off = 1; off < 1024; off <<= 1) {
    int v = (tid >= off) ? sums[tid - off] : 0;
    __syncthreads();
    sums[tid] += v;
    __syncthreads();
  }
  int run = (tid == 0) ? 0 : sums[tid - 1];
  for (int i = lo; i < hi; ++i) { rowptr[i] = run; run += deg[i]; }
  if (hi == N) rowptr[N] = sums[1023];
}

__global__ void scatter_kernel(const int* __restrict__ ei, int E, int N,
                               const int* __restrict__ rowptr, int* __restrict__ cnt,
                               int* __restrict__ srcs, int* __restrict__ dsts) {
  int j = blockIdx.x * blockDim.x + threadIdx.x;
  int Etot = E + N;
  if (j >= Etot) return;
  int s, d;
  if (j < E) { s = ei[j]; d = ei[E + j]; } else { s = j - E; d = j - E; }
  int pos = rowptr[d] + atomicAdd(&cnt[d], 1);
  srcs[pos] = s;
  dsts[pos] = d;
}

// ---------- Layer 1: edge logits (C=256, rank-1 features => scalar inputs) ----------
__global__ __launch_bounds__(256) void l1_edge_kernel(
    const float* __restrict__ x, const int* __restrict__ srcs, const int* __restrict__ dsts,
    int Etot, const float* __restrict__ Wl1, const float* __restrict__ bl1,
    const float* __restrict__ Wr1, const float* __restrict__ br1,
    const float* __restrict__ att1, float* __restrict__ elog) {
  int gtid = blockIdx.x * blockDim.x + threadIdx.x;
  int wid = gtid >> 6;
  int lane = threadIdx.x & 63;
  int base = wid << 6;
  if (base >= Etot) return;
  int c0 = lane * 4;
  float4 wl = *(const float4*)(Wl1 + c0);
  float4 wr = *(const float4*)(Wr1 + c0);
  float4 ba = *(const float4*)(bl1 + c0);
  float4 bb = *(const float4*)(br1 + c0);
  float4 at = *(const float4*)(att1 + c0);
  float cb0 = ba.x + bb.x, cb1 = ba.y + bb.y, cb2 = ba.z + bb.z, cb3 = ba.w + bb.w;
  int idx = base + lane;
  float xs = 0.f, xd = 0.f;
  if (idx < Etot) { xs = x[srcs[idx]]; xd = x[dsts[idx]]; }
  int nedge = min(64, Etot - base);
  float my_e = 0.f;
  for (int t = 0; t < nedge; ++t) {
    float xst = __shfl(xs, t, 64);
    float xdt = __shfl(xd, t, 64);
    float t0 = fmaf(xst, wl.x, fmaf(xdt, wr.x, cb0)); t0 = fmaxf(t0, SLOPE * t0);
    float t1 = fmaf(xst, wl.y, fmaf(xdt, wr.y, cb1)); t1 = fmaxf(t1, SLOPE * t1);
    float t2 = fmaf(xst, wl.z, fmaf(xdt, wr.z, cb2)); t2 = fmaxf(t2, SLOPE * t2);
    float t3 = fmaf(xst, wl.w, fmaf(xdt, wr.w, cb3)); t3 = fmaxf(t3, SLOPE * t3);
    float p = fmaf(t0, at.x, fmaf(t1, at.y, fmaf(t2, at.z, t3 * at.w)));
    p = waveReduceSum(p);
    if (lane == t) my_e = p;
  }
  if (idx < Etot) elog[idx] = my_e;
}

// ---------- Layer 1: per-dst softmax + scalar aggregation -> S1 ----------
__global__ __launch_bounds__(256) void l1_agg_kernel(
    const float* __restrict__ x, const float* __restrict__ elog,
    const int* __restrict__ srcs, const int* __restrict__ rowptr,
    int N, float* __restrict__ S1) {
  int wid = (blockIdx.x * blockDim.x + threadIdx.x) >> 6;
  int lane = threadIdx.x & 63;
  if (wid >= N) return;
  int base = rowptr[wid], end = rowptr[wid + 1];
  float m = -INFINITY;
  for (int k = base + lane; k < end; k += 64) m = fmaxf(m, elog[k]);
  m = waveReduceMax(m);
  float ps = 0.f, vs = 0.f;
  for (int k = base + lane; k < end; k += 64) {
    float p = __expf(elog[k] - m);
    ps += p;
    vs = fmaf(p, x[srcs[k]], vs);
  }
  ps = waveReduceSum(ps);
  vs = waveReduceSum(vs);
  if (lane == 0) S1[wid] = vs / ps;
}

// ---------- Weight prep: Wt[c][k] = bf16(Wcat[k][c]), c<128 -> Wl2, else Wr2 ----------
__global__ __launch_bounds__(1024) void wcvt_kernel(
    const float* __restrict__ Wl2, const float* __restrict__ Wr2,
    __hip_bfloat16* __restrict__ Wt) {
  __shared__ float tile[32][33];
  int k0 = blockIdx.y * 32, c0 = blockIdx.x * 32;
  int tx = threadIdx.x & 31, ty = threadIdx.x >> 5;
  int k = k0 + ty, c = c0 + tx;
  float v = (c < 128) ? Wl2[(size_t)k * 128 + c] : Wr2[(size_t)k * 128 + (c - 128)];
  tile[ty][tx] = v;
  __syncthreads();
  Wt[(size_t)(c0 + ty) * 256 + k0 + tx] = __float2bfloat16(tile[tx][ty]);
}

// ---------- Layer 2 transform via MFMA: h(S1) built in-register, D = h @ [Wl2|Wr2] ----------
// Tile: 128 rows x 256 cols per block, 8 waves of 64x64 (4x4 fragments of 16x16x32 bf16).
// A-frag layout: lane holds A[m = lane&15][k = (lane>>4)*8 + j], j=0..7  (m92 B^T pattern)
// C/D layout:    col = lane&15, row = (lane>>4)*4 + reg                  (m89 verified)
__global__ __launch_bounds__(512) void l2_transform_mfma(
    const float* __restrict__ S1,
    const float* __restrict__ Wl1, const float* __restrict__ bl1,
    const float* __restrict__ bias1, const float* __restrict__ prelu_w,
    const __hip_bfloat16* __restrict__ Wt,
    const float* __restrict__ bl2, const float* __restrict__ br2,
    int N, float* __restrict__ xl2, float* __restrict__ xr2) {
  int w = threadIdx.x >> 6;
  int lane = threadIdx.x & 63;
  int l15 = lane & 15, lk = lane >> 4;
  int rbase = blockIdx.x * 128 + (w & 1) * 64;
  int cbase = (w >> 1) * 64;

  float s1v[4];
#pragma unroll
  for (int mt = 0; mt < 4; ++mt) {
    int r = rbase + mt * 16 + l15;
    s1v[mt] = (r < N) ? S1[r] : 0.f;
  }

  f32x4 acc[4][4] = {};

#pragma unroll
  for (int ks = 0; ks < 8; ++ks) {
    int k0 = ks * 32 + lk * 8;
    float4 wl1a = *(const float4*)(Wl1 + k0);
    float4 wl1b = *(const float4*)(Wl1 + k0 + 4);
    float4 b1a  = *(const float4*)(bl1 + k0);
    float4 b1b  = *(const float4*)(bl1 + k0 + 4);
    float4 z1a  = *(const float4*)(bias1 + k0);
    float4 z1b  = *(const float4*)(bias1 + k0 + 4);
    float4 pwa  = *(const float4*)(prelu_w + k0);
    float4 pwb  = *(const float4*)(prelu_w + k0 + 4);
    float wv[8] = {wl1a.x, wl1a.y, wl1a.z, wl1a.w, wl1b.x, wl1b.y, wl1b.z, wl1b.w};
    float cv[8] = {b1a.x + z1a.x, b1a.y + z1a.y, b1a.z + z1a.z, b1a.w + z1a.w,
                   b1b.x + z1b.x, b1b.y + z1b.y, b1b.z + z1b.z, b1b.w + z1b.w};
    float pv[8] = {pwa.x, pwa.y, pwa.z, pwa.w, pwb.x, pwb.y, pwb.z, pwb.w};

    short8 afrag[4];
#pragma unroll
    for (int mt = 0; mt < 4; ++mt) {
      short8 a;
#pragma unroll
      for (int j = 0; j < 8; ++j) {
        float t = fmaf(wv[j], s1v[mt], cv[j]);
        t = (t > 0.f) ? t : pv[j] * t;
        __hip_bfloat16 hb = __float2bfloat16(t);
        a[j] = *reinterpret_cast<short*>(&hb);
      }
      afrag[mt] = a;
    }

    short8 bfrag[4];
#pragma unroll
    for (int nt = 0; nt < 4; ++nt) {
      int col = cbase + nt * 16 + l15;
      bfrag[nt] = *(const short8*)(Wt + (size_t)col * 256 + k0);
    }

#pragma unroll
    for (int mt = 0; mt < 4; ++mt)
#pragma unroll
      for (int nt = 0; nt < 4; ++nt)
        acc[mt][nt] = __builtin_amdgcn_mfma_f32_16x16x32_bf16(afrag[mt], bfrag[nt],
                                                              acc[mt][nt], 0, 0, 0);
  }

#pragma unroll
  for (int mt = 0; mt < 4; ++mt) {
#pragma unroll
    for (int nt = 0; nt < 4; ++nt) {
      int col = cbase + nt * 16 + l15;
      float bias;
      float* dst;
      int cc;
      if (col < 128) { bias = bl2[col]; dst = xl2; cc = col; }
      else           { bias = br2[col - 128]; dst = xr2; cc = col - 128; }
#pragma unroll
      for (int r = 0; r < 4; ++r) {
        int row = rbase + mt * 16 + lk * 4 + r;
        if (row < N) dst[(size_t)row * 128 + cc] = acc[mt][nt][r] + bias;
      }
    }
  }
}

// ---------- Layer 2: edge logits (C=128) ----------
__global__ __launch_bounds__(256) void l2_edge_kernel(
    const float* __restrict__ xl2, const float* __restrict__ xr2,
    const int* __restrict__ srcs, const int* __restrict__ dsts, int Etot,
    const float* __restrict__ att2, float* __restrict__ elog) {
  int gtid = blockIdx.x * blockDim.x + threadIdx.x;
  int wid = gtid >> 6;
  int lane = threadIdx.x & 63;
  int base = wid << 6;
  if (base >= Etot) return;
  int c0 = lane * 2;
  float2 at = *(const float2*)(att2 + c0);
  int idx = base + lane;
  int sv = 0, dv = 0;
  if (idx < Etot) { sv = srcs[idx]; dv = dsts[idx]; }
  int nedge = min(64, Etot - base);
  float my_e = 0.f;
  for (int t = 0; t < nedge; ++t) {
    int s = __shfl(sv, t, 64);
    int d = __shfl(dv, t, 64);
    float2 a = *(const float2*)(xl2 + (size_t)s * 128 + c0);
    float2 b = *(const float2*)(xr2 + (size_t)d * 128 + c0);
    float v0 = a.x + b.x; v0 = fmaxf(v0, SLOPE * v0);
    float v1 = a.y + b.y; v1 = fmaxf(v1, SLOPE * v1);
    float p = fmaf(v0, at.x, v1 * at.y);
    p = waveReduceSum(p);
    if (lane == t) my_e = p;
  }
  if (idx < Etot) elog[idx] = my_e;
}

// ---------- Layer 2: per-dst softmax + row aggregation -> out ----------
__global__ __launch_bounds__(256) void l2_agg_kernel(
    const float* __restrict__ xl2, const float* __restrict__ elog,
    const int* __restrict__ srcs, const int* __restrict__ rowptr,
    const float* __restrict__ bias2, int N, float* __restrict__ out) {
  int wid = (blockIdx.x * blockDim.x + threadIdx.x) >> 6;
  int lane = threadIdx.x & 63;
  if (wid >= N) return;
  int base = rowptr[wid], end = rowptr[wid + 1];
  int c0 = lane * 2;
  float m = -INFINITY;
  for (int k = base + lane; k < end; k += 64) m = fmaxf(m, elog[k]);
  m = waveReduceMax(m);
  float ps = 0.f, a0 = 0.f, a1 = 0.f;
  for (int kb = base; kb < end; kb += 64) {
    int k = kb + lane;
    float p = 0.f; int sv = 0;
    if (k < end) { p = __expf(elog[k] - m); sv = srcs[k]; }
    ps += p;
    int lim = min(64, end - kb);
    for (int t = 0; t < lim; ++t) {
      float alpha = __shfl(p, t, 64);
      int s = __shfl(sv, t, 64);
      float2 row = *(const float2*)(xl2 + (size_t)s * 128 + c0);
      a0 = fmaf(alpha, row.x, a0);
      a1 = fmaf(alpha, row.y, a1);
    }
  }
  ps = waveReduceSum(ps);
  float inv = 1.f / ps;
  float2 bz = *(const float2*)(bias2 + c0);
  float2 res;
  res.x = fmaf(a0, inv, bz.x);
  res.y = fmaf(a1, inv, bz.y);
  *(float2*)(out + (size_t)wid * 128 + c0) = res;
}

extern "C" void kernel_launch(void* const* d_in, const int* in_sizes, int n_in,
                              void* d_out, int out_size, void* d_ws, size_t ws_size,
                              hipStream_t stream) {
  const float* x      = (const float*)d_in[0];
  const int*   ei     = (const int*)d_in[1];
  const float* Wl1    = (const float*)d_in[2];
  const float* bl1    = (const float*)d_in[3];
  const float* Wr1    = (const float*)d_in[4];
  const float* br1    = (const float*)d_in[5];
  const float* att1   = (const float*)d_in[6];
  const float* bias1  = (const float*)d_in[7];
  const float* prelu  = (const float*)d_in[8];
  const float* Wl2    = (const float*)d_in[9];
  const float* bl2    = (const float*)d_in[10];
  const float* Wr2    = (const float*)d_in[11];
  const float* br2    = (const float*)d_in[12];
  const float* att2   = (const float*)d_in[13];
  const float* bias2  = (const float*)d_in[14];
  float* out = (float*)d_out;

  int N = in_sizes[0];       // x is [N,1]
  int E = in_sizes[1] / 2;   // edge_index [2,E]
  int Etot = E + N;          // + self loops

  char* ws = (char*)d_ws;
  size_t off = 0;
  auto alloc = [&](size_t bytes) -> void* {
    void* p = ws + off;
    off = (off + bytes + 255) & ~(size_t)255;
    return p;
  };
  float* S1     = (float*)alloc((size_t)N * 4);
  float* elog   = (float*)alloc((size_t)Etot * 4);
  float* xl2    = (float*)alloc((size_t)N * 128 * 4);
  float* xr2    = (float*)alloc((size_t)N * 128 * 4);
  int*   deg    = (int*)alloc((size_t)N * 4);
  int*   cnt    = (int*)alloc((size_t)N * 4);
  int*   rowptr = (int*)alloc((size_t)(N + 1) * 4);
  int*   srcs   = (int*)alloc((size_t)Etot * 4);
  int*   dsts   = (int*)alloc((size_t)Etot * 4);
  __hip_bfloat16* Wt = (__hip_bfloat16*)alloc((size_t)256 * 256 * 2);
  (void)ws_size; (void)n_in; (void)out_size;

  hipMemsetAsync(deg, 0, (size_t)N * 4, stream);
  hipMemsetAsync(cnt, 0, (size_t)N * 4, stream);

  int gE = (Etot + 255) / 256;
  count_kernel<<<gE, 256, 0, stream>>>(ei, E, N, deg);
  scan_kernel<<<1, 1024, 0, stream>>>(deg, N, rowptr);
  scatter_kernel<<<gE, 256, 0, stream>>>(ei, E, N, rowptr, cnt, srcs, dsts);

  // weight prep can overlap CSR build conceptually; stream-serial is fine (tiny)
  wcvt_kernel<<<dim3(8, 8), 1024, 0, stream>>>(Wl2, Wr2, Wt);

  int gEdgeWave = (Etot + 255) / 256;  // 4 waves/block, 64 edges/wave
  l1_edge_kernel<<<gEdgeWave, 256, 0, stream>>>(x, srcs, dsts, Etot, Wl1, bl1, Wr1, br1, att1, elog);
  l1_agg_kernel<<<(N + 3) / 4, 256, 0, stream>>>(x, elog, srcs, rowptr, N, S1);

  l2_transform_mfma<<<(N + 127) / 128, 512, 0, stream>>>(S1, Wl1, bl1, bias1, prelu,
                                                         Wt, bl2, br2, N, xl2, xr2);
  l2_edge_kernel<<<gEdgeWave, 256, 0, stream>>>(xl2, xr2, srcs, dsts, Etot, att2, elog);
  l2_agg_kernel<<<(N + 3) / 4, 256, 0, stream>>>(xl2, elog, srcs, rowptr, bias2, N, out);
}

// Round 3
// 480.836 us; speedup vs baseline: 1.8290x; 1.1175x over previous
//
#include <hip/hip_runtime.h>
#include <hip/hip_bf16.h>

#define SLOPE 0.2f

typedef __attribute__((ext_vector_type(8))) short short8;
typedef __attribute__((ext_vector_type(4))) float f32x4;

static __device__ __forceinline__ float waveReduceSum(float v) {
#pragma unroll
  for (int off = 32; off > 0; off >>= 1) v += __shfl_xor(v, off, 64);
  return v;
}

// ---------- CSR build ----------
__global__ void count_kernel(const int* __restrict__ ei, int E, int N, int* __restrict__ deg) {
  int j = blockIdx.x * blockDim.x + threadIdx.x;
  int Etot = E + N;
  if (j >= Etot) return;
  int d = (j < E) ? ei[E + j] : (j - E);
  atomicAdd(&deg[d], 1);
}

__global__ __launch_bounds__(1024) void scan_kernel(const int* __restrict__ deg, int N,
                                                    int* __restrict__ rowptr) {
  __shared__ int sums[1024];
  int tid = threadIdx.x;
  int chunk = (N + 1023) >> 10;
  int lo = tid * chunk;
  int hi = min(lo + chunk, N);
  int s = 0;
  for (int i = lo; i < hi; ++i) s += deg[i];
  sums[tid] = s;
  __syncthreads();
  for (int off = 1; off < 1024; off <<= 1) {
    int v = (tid >= off) ? sums[tid - off] : 0;
    __syncthreads();
    sums[tid] += v;
    __syncthreads();
  }
  int run = (tid == 0) ? 0 : sums[tid - 1];
  for (int i = lo; i < hi; ++i) { rowptr[i] = run; run += deg[i]; }
  if (hi == N) rowptr[N] = sums[1023];
}

__global__ void scatter_kernel(const int* __restrict__ ei, int E, int N,
                               const int* __restrict__ rowptr, int* __restrict__ cnt,
                               int* __restrict__ srcs) {
  int j = blockIdx.x * blockDim.x + threadIdx.x;
  int Etot = E + N;
  if (j >= Etot) return;
  int s, d;
  if (j < E) { s = ei[j]; d = ei[E + j]; } else { s = j - E; d = j - E; }
  int pos = rowptr[d] + atomicAdd(&cnt[d], 1);
  srcs[pos] = s;
}

// ---------- Layer 1 fused: online softmax + scalar aggregation -> S1 ----------
// One wave per dst node. Channels (256) split 4/lane; per edge: logit dot via
// butterfly reduce, then wave-uniform online-softmax update with xs in hand.
__global__ __launch_bounds__(256) void l1_fused_kernel(
    const float* __restrict__ x, const int* __restrict__ srcs,
    const int* __restrict__ rowptr, int N,
    const float* __restrict__ Wl1, const float* __restrict__ bl1,
    const float* __restrict__ Wr1, const float* __restrict__ br1,
    const float* __restrict__ att1, float* __restrict__ S1) {
  int wid = (blockIdx.x * blockDim.x + threadIdx.x) >> 6;
  int lane = threadIdx.x & 63;
  if (wid >= N) return;
  int c0 = lane * 4;
  float4 wl = *(const float4*)(Wl1 + c0);
  float4 wr = *(const float4*)(Wr1 + c0);
  float4 ba = *(const float4*)(bl1 + c0);
  float4 bb = *(const float4*)(br1 + c0);
  float4 at = *(const float4*)(att1 + c0);
  float xd = x[wid];
  // fold dst-side transform + biases once per wave
  float cc0 = fmaf(xd, wr.x, ba.x + bb.x);
  float cc1 = fmaf(xd, wr.y, ba.y + bb.y);
  float cc2 = fmaf(xd, wr.z, ba.z + bb.z);
  float cc3 = fmaf(xd, wr.w, ba.w + bb.w);

  int base = rowptr[wid], end = rowptr[wid + 1];
  float m = -INFINITY, S = 0.f, vs = 0.f;
  for (int k = base; k < end; ++k) {
    float xs = x[srcs[k]];
    float t0 = fmaf(xs, wl.x, cc0); t0 = fmaxf(t0, SLOPE * t0);
    float t1 = fmaf(xs, wl.y, cc1); t1 = fmaxf(t1, SLOPE * t1);
    float t2 = fmaf(xs, wl.z, cc2); t2 = fmaxf(t2, SLOPE * t2);
    float t3 = fmaf(xs, wl.w, cc3); t3 = fmaxf(t3, SLOPE * t3);
    float p = fmaf(t0, at.x, fmaf(t1, at.y, fmaf(t2, at.z, t3 * at.w)));
    p = waveReduceSum(p);  // edge logit, uniform across wave
    float mn = fmaxf(m, p);
    float sc = __expf(m - mn);  // first iter: exp(-inf)=0
    float w  = __expf(p - mn);
    S  = fmaf(S, sc, w);
    vs = fmaf(vs, sc, w * xs);
    m = mn;
  }
  if (lane == 0) S1[wid] = vs / S;
}

// ---------- Weight prep: Wt[c][k] = bf16(Wcat[k][c]), c<128 -> Wl2, else Wr2 ----------
__global__ __launch_bounds__(1024) void wcvt_kernel(
    const float* __restrict__ Wl2, const float* __restrict__ Wr2,
    __hip_bfloat16* __restrict__ Wt) {
  __shared__ float tile[32][33];
  int k0 = blockIdx.y * 32, c0 = blockIdx.x * 32;
  int tx = threadIdx.x & 31, ty = threadIdx.x >> 5;
  int k = k0 + ty, c = c0 + tx;
  float v = (c < 128) ? Wl2[(size_t)k * 128 + c] : Wr2[(size_t)k * 128 + (c - 128)];
  tile[ty][tx] = v;
  __syncthreads();
  Wt[(size_t)(c0 + ty) * 256 + k0 + tx] = __float2bfloat16(tile[tx][ty]);
}

// ---------- Layer 2 transform via MFMA: h(S1) built in-register, D = h @ [Wl2|Wr2] ----------
__global__ __launch_bounds__(512) void l2_transform_mfma(
    const float* __restrict__ S1,
    const float* __restrict__ Wl1, const float* __restrict__ bl1,
    const float* __restrict__ bias1, const float* __restrict__ prelu_w,
    const __hip_bfloat16* __restrict__ Wt,
    const float* __restrict__ bl2, const float* __restrict__ br2,
    int N, float* __restrict__ xl2, float* __restrict__ xr2) {
  int w = threadIdx.x >> 6;
  int lane = threadIdx.x & 63;
  int l15 = lane & 15, lk = lane >> 4;
  int rbase = blockIdx.x * 128 + (w & 1) * 64;
  int cbase = (w >> 1) * 64;

  float s1v[4];
#pragma unroll
  for (int mt = 0; mt < 4; ++mt) {
    int r = rbase + mt * 16 + l15;
    s1v[mt] = (r < N) ? S1[r] : 0.f;
  }

  f32x4 acc[4][4] = {};

#pragma unroll
  for (int ks = 0; ks < 8; ++ks) {
    int k0 = ks * 32 + lk * 8;
    float4 wl1a = *(const float4*)(Wl1 + k0);
    float4 wl1b = *(const float4*)(Wl1 + k0 + 4);
    float4 b1a  = *(const float4*)(bl1 + k0);
    float4 b1b  = *(const float4*)(bl1 + k0 + 4);
    float4 z1a  = *(const float4*)(bias1 + k0);
    float4 z1b  = *(const float4*)(bias1 + k0 + 4);
    float4 pwa  = *(const float4*)(prelu_w + k0);
    float4 pwb  = *(const float4*)(prelu_w + k0 + 4);
    float wv[8] = {wl1a.x, wl1a.y, wl1a.z, wl1a.w, wl1b.x, wl1b.y, wl1b.z, wl1b.w};
    float cv[8] = {b1a.x + z1a.x, b1a.y + z1a.y, b1a.z + z1a.z, b1a.w + z1a.w,
                   b1b.x + z1b.x, b1b.y + z1b.y, b1b.z + z1b.z, b1b.w + z1b.w};
    float pv[8] = {pwa.x, pwa.y, pwa.z, pwa.w, pwb.x, pwb.y, pwb.z, pwb.w};

    short8 afrag[4];
#pragma unroll
    for (int mt = 0; mt < 4; ++mt) {
      short8 a;
#pragma unroll
      for (int j = 0; j < 8; ++j) {
        float t = fmaf(wv[j], s1v[mt], cv[j]);
        t = (t > 0.f) ? t : pv[j] * t;
        __hip_bfloat16 hb = __float2bfloat16(t);
        a[j] = *reinterpret_cast<short*>(&hb);
      }
      afrag[mt] = a;
    }

    short8 bfrag[4];
#pragma unroll
    for (int nt = 0; nt < 4; ++nt) {
      int col = cbase + nt * 16 + l15;
      bfrag[nt] = *(const short8*)(Wt + (size_t)col * 256 + k0);
    }

#pragma unroll
    for (int mt = 0; mt < 4; ++mt)
#pragma unroll
      for (int nt = 0; nt < 4; ++nt)
        acc[mt][nt] = __builtin_amdgcn_mfma_f32_16x16x32_bf16(afrag[mt], bfrag[nt],
                                                              acc[mt][nt], 0, 0, 0);
  }

#pragma unroll
  for (int mt = 0; mt < 4; ++mt) {
#pragma unroll
    for (int nt = 0; nt < 4; ++nt) {
      int col = cbase + nt * 16 + l15;
      float bias;
      float* dst;
      int cc;
      if (col < 128) { bias = bl2[col]; dst = xl2; cc = col; }
      else           { bias = br2[col - 128]; dst = xr2; cc = col - 128; }
#pragma unroll
      for (int r = 0; r < 4; ++r) {
        int row = rbase + mt * 16 + lk * 4 + r;
        if (row < N) dst[(size_t)row * 128 + cc] = acc[mt][nt][r] + bias;
      }
    }
  }
}

// ---------- Layer 2 fused: online softmax + row aggregation -> out ----------
// One wave per dst node, 2 channels/lane. Src row loaded ONCE per edge and
// consumed for both the logit dot and the aggregation.
__global__ __launch_bounds__(256) void l2_fused_kernel(
    const float* __restrict__ xl2, const float* __restrict__ xr2,
    const int* __restrict__ srcs, const int* __restrict__ rowptr,
    const float* __restrict__ att2, const float* __restrict__ bias2,
    int N, float* __restrict__ out) {
  int wid = (blockIdx.x * blockDim.x + threadIdx.x) >> 6;
  int lane = threadIdx.x & 63;
  if (wid >= N) return;
  int c0 = lane * 2;
  float2 at = *(const float2*)(att2 + c0);
  float2 dr = *(const float2*)(xr2 + (size_t)wid * 128 + c0);
  int base = rowptr[wid], end = rowptr[wid + 1];
  float m = -INFINITY, S = 0.f, a0 = 0.f, a1 = 0.f;
  for (int k = base; k < end; ++k) {
    int s = srcs[k];
    float2 sr = *(const float2*)(xl2 + (size_t)s * 128 + c0);
    float v0 = sr.x + dr.x; v0 = fmaxf(v0, SLOPE * v0);
    float v1 = sr.y + dr.y; v1 = fmaxf(v1, SLOPE * v1);
    float p = fmaf(v0, at.x, v1 * at.y);
    p = waveReduceSum(p);  // edge logit, uniform
    float mn = fmaxf(m, p);
    float sc = __expf(m - mn);
    float w  = __expf(p - mn);
    S  = fmaf(S, sc, w);
    a0 = fmaf(a0, sc, w * sr.x);
    a1 = fmaf(a1, sc, w * sr.y);
    m = mn;
  }
  float inv = 1.f / S;
  float2 bz = *(const float2*)(bias2 + c0);
  float2 res;
  res.x = fmaf(a0, inv, bz.x);
  res.y = fmaf(a1, inv, bz.y);
  *(float2*)(out + (size_t)wid * 128 + c0) = res;
}

extern "C" void kernel_launch(void* const* d_in, const int* in_sizes, int n_in,
                              void* d_out, int out_size, void* d_ws, size_t ws_size,
                              hipStream_t stream) {
  const float* x      = (const float*)d_in[0];
  const int*   ei     = (const int*)d_in[1];
  const float* Wl1    = (const float*)d_in[2];
  const float* bl1    = (const float*)d_in[3];
  const float* Wr1    = (const float*)d_in[4];
  const float* br1    = (const float*)d_in[5];
  const float* att1   = (const float*)d_in[6];
  const float* bias1  = (const float*)d_in[7];
  const float* prelu  = (const float*)d_in[8];
  const float* Wl2    = (const float*)d_in[9];
  const float* bl2    = (const float*)d_in[10];
  const float* Wr2    = (const float*)d_in[11];
  const float* br2    = (const float*)d_in[12];
  const float* att2   = (const float*)d_in[13];
  const float* bias2  = (const float*)d_in[14];
  float* out = (float*)d_out;

  int N = in_sizes[0];       // x is [N,1]
  int E = in_sizes[1] / 2;   // edge_index [2,E]
  int Etot = E + N;          // + self loops

  char* ws = (char*)d_ws;
  size_t off = 0;
  auto alloc = [&](size_t bytes) -> void* {
    void* p = ws + off;
    off = (off + bytes + 255) & ~(size_t)255;
    return p;
  };
  float* S1     = (float*)alloc((size_t)N * 4);
  float* xl2    = (float*)alloc((size_t)N * 128 * 4);
  float* xr2    = (float*)alloc((size_t)N * 128 * 4);
  int*   deg    = (int*)alloc((size_t)N * 4);
  int*   cnt    = (int*)alloc((size_t)N * 4);
  int*   rowptr = (int*)alloc((size_t)(N + 1) * 4);
  int*   srcs   = (int*)alloc((size_t)Etot * 4);
  __hip_bfloat16* Wt = (__hip_bfloat16*)alloc((size_t)256 * 256 * 2);
  (void)ws_size; (void)n_in; (void)out_size;

  hipMemsetAsync(deg, 0, (size_t)N * 4, stream);
  hipMemsetAsync(cnt, 0, (size_t)N * 4, stream);

  int gE = (Etot + 255) / 256;
  count_kernel<<<gE, 256, 0, stream>>>(ei, E, N, deg);
  scan_kernel<<<1, 1024, 0, stream>>>(deg, N, rowptr);
  scatter_kernel<<<gE, 256, 0, stream>>>(ei, E, N, rowptr, cnt, srcs);

  wcvt_kernel<<<dim3(8, 8), 1024, 0, stream>>>(Wl2, Wr2, Wt);

  l1_fused_kernel<<<(N + 3) / 4, 256, 0, stream>>>(x, srcs, rowptr, N,
                                                   Wl1, bl1, Wr1, br1, att1, S1);
  l2_transform_mfma<<<(N + 127) / 128, 512, 0, stream>>>(S1, Wl1, bl1, bias1, prelu,
                                                         Wt, bl2, br2, N, xl2, xr2);
  l2_fused_kernel<<<(N + 3) / 4, 256, 0, stream>>>(xl2, xr2, srcs, rowptr,
                                                   att2, bias2, N, out);
}

// Round 4
// 381.033 us; speedup vs baseline: 2.3081x; 1.2619x over previous
//
#include <hip/hip_runtime.h>
#include <hip/hip_bf16.h>

#define SLOPE 0.2f

typedef __attribute__((ext_vector_type(8))) short short8;
typedef __attribute__((ext_vector_type(4))) float f32x4;

static __device__ __forceinline__ float bf2f(unsigned short u) {
  unsigned int x = ((unsigned int)u) << 16;
  return __uint_as_float(x);
}
static __device__ __forceinline__ unsigned short f2bf(float f) {
  __hip_bfloat16 h = __float2bfloat16(f);
  return *reinterpret_cast<unsigned short*>(&h);
}

// Packed 4-value wave reduce: lanes hold partials q0..q3 (one per edge).
// Returns p0..p3 = full 64-lane sums, broadcast to all lanes.
// 7 shfl + 4 broadcast-shfl for 4 values (vs 24 for 4 independent butterflies).
static __device__ __forceinline__ void packedReduce4(
    float q0, float q1, float q2, float q3,
    float& p0, float& p1, float& p2, float& p3) {
  int lane = threadIdx.x & 63;
  float u = (lane & 1) ? q1 : q0;   // keep
  float v = (lane & 1) ? q0 : q1;   // give
  u += __shfl_xor(v, 1, 64);
  float w = (lane & 1) ? q3 : q2;
  float z = (lane & 1) ? q2 : q3;
  w += __shfl_xor(z, 1, 64);
  float a = (lane & 2) ? w : u;     // keep
  float b = (lane & 2) ? u : w;     // give
  a += __shfl_xor(b, 2, 64);
  a += __shfl_xor(a, 4, 64);
  a += __shfl_xor(a, 8, 64);
  a += __shfl_xor(a, 16, 64);
  a += __shfl_xor(a, 32, 64);
  // lane l now holds total of series (l & 3)
  p0 = __shfl(a, 0, 64);
  p1 = __shfl(a, 1, 64);
  p2 = __shfl(a, 2, 64);
  p3 = __shfl(a, 3, 64);
}

// ---------- CSR build ----------
__global__ void count_kernel(const int* __restrict__ ei, int E, int N, int* __restrict__ deg) {
  int j = blockIdx.x * blockDim.x + threadIdx.x;
  int Etot = E + N;
  if (j >= Etot) return;
  int d = (j < E) ? ei[E + j] : (j - E);
  atomicAdd(&deg[d], 1);
}

__global__ __launch_bounds__(1024) void scan_kernel(const int* __restrict__ deg, int N,
                                                    int* __restrict__ rowptr) {
  __shared__ int sums[1024];
  int tid = threadIdx.x;
  int chunk = (N + 1023) >> 10;
  int lo = tid * chunk;
  int hi = min(lo + chunk, N);
  int s = 0;
  for (int i = lo; i < hi; ++i) s += deg[i];
  sums[tid] = s;
  __syncthreads();
  for (int off = 1; off < 1024; off <<= 1) {
    int v = (tid >= off) ? sums[tid - off] : 0;
    __syncthreads();
    sums[tid] += v;
    __syncthreads();
  }
  int run = (tid == 0) ? 0 : sums[tid - 1];
  for (int i = lo; i < hi; ++i) { rowptr[i] = run; run += deg[i]; }
  if (hi == N) rowptr[N] = sums[1023];
}

__global__ void scatter_kernel(const int* __restrict__ ei, int E, int N,
                               const int* __restrict__ rowptr, int* __restrict__ cnt,
                               int* __restrict__ srcs) {
  int j = blockIdx.x * blockDim.x + threadIdx.x;
  int Etot = E + N;
  if (j >= Etot) return;
  int s, d;
  if (j < E) { s = ei[j]; d = ei[E + j]; } else { s = j - E; d = j - E; }
  int pos = rowptr[d] + atomicAdd(&cnt[d], 1);
  srcs[pos] = s;
}

// ---------- Layer 1 fused: online softmax + scalar aggregation -> S1 ----------
// One wave per dst; 4 channels/lane; 4 edges per iteration (packed butterfly).
__global__ __launch_bounds__(256) void l1_fused_kernel(
    const float* __restrict__ x, const int* __restrict__ srcs,
    const int* __restrict__ rowptr, int N,
    const float* __restrict__ Wl1, const float* __restrict__ bl1,
    const float* __restrict__ Wr1, const float* __restrict__ br1,
    const float* __restrict__ att1, float* __restrict__ S1) {
  int wid = (blockIdx.x * blockDim.x + threadIdx.x) >> 6;
  int lane = threadIdx.x & 63;
  if (wid >= N) return;
  int c0 = lane * 4;
  float4 wl = *(const float4*)(Wl1 + c0);
  float4 wr = *(const float4*)(Wr1 + c0);
  float4 ba = *(const float4*)(bl1 + c0);
  float4 bb = *(const float4*)(br1 + c0);
  float4 at = *(const float4*)(att1 + c0);
  float xd = x[wid];
  float cc0 = fmaf(xd, wr.x, ba.x + bb.x);
  float cc1 = fmaf(xd, wr.y, ba.y + bb.y);
  float cc2 = fmaf(xd, wr.z, ba.z + bb.z);
  float cc3 = fmaf(xd, wr.w, ba.w + bb.w);

  int base = rowptr[wid], end = rowptr[wid + 1];
  float m = -INFINITY, S = 0.f, vs = 0.f;
  for (int k0 = base; k0 < end; k0 += 4) {
    int k1 = min(k0 + 1, end - 1);
    int k2 = min(k0 + 2, end - 1);
    int k3 = min(k0 + 3, end - 1);
    float xs0 = x[srcs[k0]];
    float xs1 = x[srcs[k1]];
    float xs2 = x[srcs[k2]];
    float xs3 = x[srcs[k3]];

    float q0, q1, q2, q3;
    {
      float t0, t1, t2, t3;
#define L1DOT(xs, q)                                              \
      t0 = fmaf(xs, wl.x, cc0); t0 = fmaxf(t0, SLOPE * t0);       \
      t1 = fmaf(xs, wl.y, cc1); t1 = fmaxf(t1, SLOPE * t1);       \
      t2 = fmaf(xs, wl.z, cc2); t2 = fmaxf(t2, SLOPE * t2);       \
      t3 = fmaf(xs, wl.w, cc3); t3 = fmaxf(t3, SLOPE * t3);       \
      q = fmaf(t0, at.x, fmaf(t1, at.y, fmaf(t2, at.z, t3 * at.w)));
      L1DOT(xs0, q0) L1DOT(xs1, q1) L1DOT(xs2, q2) L1DOT(xs3, q3)
#undef L1DOT
    }
    float p0, p1, p2, p3;
    packedReduce4(q0, q1, q2, q3, p0, p1, p2, p3);
    if (k0 + 1 >= end) p1 = -INFINITY;
    if (k0 + 2 >= end) p2 = -INFINITY;
    if (k0 + 3 >= end) p3 = -INFINITY;

    float mn = fmaxf(fmaxf(m, fmaxf(p0, p1)), fmaxf(p2, p3));
    float sc = __expf(m - mn);
    float w0 = __expf(p0 - mn), w1 = __expf(p1 - mn);
    float w2 = __expf(p2 - mn), w3 = __expf(p3 - mn);
    S  = fmaf(S, sc, (w0 + w1) + (w2 + w3));
    vs = fmaf(vs, sc, fmaf(w0, xs0, fmaf(w1, xs1, fmaf(w2, xs2, w3 * xs3))));
    m = mn;
  }
  if (lane == 0) S1[wid] = vs / S;
}

// ---------- Weight prep: Wt[c][k] = bf16(Wcat[k][c]), c<128 -> Wl2, else Wr2 ----------
__global__ __launch_bounds__(1024) void wcvt_kernel(
    const float* __restrict__ Wl2, const float* __restrict__ Wr2,
    __hip_bfloat16* __restrict__ Wt) {
  __shared__ float tile[32][33];
  int k0 = blockIdx.y * 32, c0 = blockIdx.x * 32;
  int tx = threadIdx.x & 31, ty = threadIdx.x >> 5;
  int k = k0 + ty, c = c0 + tx;
  float v = (c < 128) ? Wl2[(size_t)k * 128 + c] : Wr2[(size_t)k * 128 + (c - 128)];
  tile[ty][tx] = v;
  __syncthreads();
  Wt[(size_t)(c0 + ty) * 256 + k0 + tx] = __float2bfloat16(tile[tx][ty]);
}

// ---------- Layer 2 transform via MFMA -> bf16 xl2/xr2 ----------
__global__ __launch_bounds__(512) void l2_transform_mfma(
    const float* __restrict__ S1,
    const float* __restrict__ Wl1, const float* __restrict__ bl1,
    const float* __restrict__ bias1, const float* __restrict__ prelu_w,
    const __hip_bfloat16* __restrict__ Wt,
    const float* __restrict__ bl2, const float* __restrict__ br2,
    int N, unsigned short* __restrict__ xl2b, unsigned short* __restrict__ xr2b) {
  int w = threadIdx.x >> 6;
  int lane = threadIdx.x & 63;
  int l15 = lane & 15, lk = lane >> 4;
  int rbase = blockIdx.x * 128 + (w & 1) * 64;
  int cbase = (w >> 1) * 64;

  float s1v[4];
#pragma unroll
  for (int mt = 0; mt < 4; ++mt) {
    int r = rbase + mt * 16 + l15;
    s1v[mt] = (r < N) ? S1[r] : 0.f;
  }

  f32x4 acc[4][4] = {};

#pragma unroll
  for (int ks = 0; ks < 8; ++ks) {
    int k0 = ks * 32 + lk * 8;
    float4 wl1a = *(const float4*)(Wl1 + k0);
    float4 wl1b = *(const float4*)(Wl1 + k0 + 4);
    float4 b1a  = *(const float4*)(bl1 + k0);
    float4 b1b  = *(const float4*)(bl1 + k0 + 4);
    float4 z1a  = *(const float4*)(bias1 + k0);
    float4 z1b  = *(const float4*)(bias1 + k0 + 4);
    float4 pwa  = *(const float4*)(prelu_w + k0);
    float4 pwb  = *(const float4*)(prelu_w + k0 + 4);
    float wv[8] = {wl1a.x, wl1a.y, wl1a.z, wl1a.w, wl1b.x, wl1b.y, wl1b.z, wl1b.w};
    float cv[8] = {b1a.x + z1a.x, b1a.y + z1a.y, b1a.z + z1a.z, b1a.w + z1a.w,
                   b1b.x + z1b.x, b1b.y + z1b.y, b1b.z + z1b.z, b1b.w + z1b.w};
    float pv[8] = {pwa.x, pwa.y, pwa.z, pwa.w, pwb.x, pwb.y, pwb.z, pwb.w};

    short8 afrag[4];
#pragma unroll
    for (int mt = 0; mt < 4; ++mt) {
      short8 a;
#pragma unroll
      for (int j = 0; j < 8; ++j) {
        float t = fmaf(wv[j], s1v[mt], cv[j]);
        t = (t > 0.f) ? t : pv[j] * t;
        a[j] = (short)f2bf(t);
      }
      afrag[mt] = a;
    }

    short8 bfrag[4];
#pragma unroll
    for (int nt = 0; nt < 4; ++nt) {
      int col = cbase + nt * 16 + l15;
      bfrag[nt] = *(const short8*)(Wt + (size_t)col * 256 + k0);
    }

#pragma unroll
    for (int mt = 0; mt < 4; ++mt)
#pragma unroll
      for (int nt = 0; nt < 4; ++nt)
        acc[mt][nt] = __builtin_amdgcn_mfma_f32_16x16x32_bf16(afrag[mt], bfrag[nt],
                                                              acc[mt][nt], 0, 0, 0);
  }

#pragma unroll
  for (int mt = 0; mt < 4; ++mt) {
#pragma unroll
    for (int nt = 0; nt < 4; ++nt) {
      int col = cbase + nt * 16 + l15;
      float bias;
      unsigned short* dst;
      int cc;
      if (col < 128) { bias = bl2[col]; dst = xl2b; cc = col; }
      else           { bias = br2[col - 128]; dst = xr2b; cc = col - 128; }
#pragma unroll
      for (int r = 0; r < 4; ++r) {
        int row = rbase + mt * 16 + lk * 4 + r;
        if (row < N) dst[(size_t)row * 128 + cc] = f2bf(acc[mt][nt][r] + bias);
      }
    }
  }
}

// ---------- Layer 2 fused: online softmax + row aggregation -> out ----------
// One wave per dst; 2 channels/lane (bf16 rows); 4 edges per iteration.
__global__ __launch_bounds__(256) void l2_fused_kernel(
    const unsigned short* __restrict__ xl2b, const unsigned short* __restrict__ xr2b,
    const int* __restrict__ srcs, const int* __restrict__ rowptr,
    const float* __restrict__ att2, const float* __restrict__ bias2,
    int N, float* __restrict__ out) {
  int wid = (blockIdx.x * blockDim.x + threadIdx.x) >> 6;
  int lane = threadIdx.x & 63;
  if (wid >= N) return;
  int c0 = lane * 2;
  float2 at = *(const float2*)(att2 + c0);
  ushort2 dru = *(const ushort2*)(xr2b + (size_t)wid * 128 + c0);
  float drx = bf2f(dru.x), dry = bf2f(dru.y);
  int base = rowptr[wid], end = rowptr[wid + 1];
  float m = -INFINITY, S = 0.f, a0 = 0.f, a1 = 0.f;
  for (int k0 = base; k0 < end; k0 += 4) {
    int k1 = min(k0 + 1, end - 1);
    int k2 = min(k0 + 2, end - 1);
    int k3 = min(k0 + 3, end - 1);
    int s0 = srcs[k0], s1 = srcs[k1], s2 = srcs[k2], s3 = srcs[k3];
    ushort2 u0 = *(const ushort2*)(xl2b + (size_t)s0 * 128 + c0);
    ushort2 u1 = *(const ushort2*)(xl2b + (size_t)s1 * 128 + c0);
    ushort2 u2 = *(const ushort2*)(xl2b + (size_t)s2 * 128 + c0);
    ushort2 u3 = *(const ushort2*)(xl2b + (size_t)s3 * 128 + c0);
    float r0x = bf2f(u0.x), r0y = bf2f(u0.y);
    float r1x = bf2f(u1.x), r1y = bf2f(u1.y);
    float r2x = bf2f(u2.x), r2y = bf2f(u2.y);
    float r3x = bf2f(u3.x), r3y = bf2f(u3.y);

    float q0, q1, q2, q3;
    {
      float v0, v1;
#define L2DOT(rx, ry, q)                                        \
      v0 = rx + drx; v0 = fmaxf(v0, SLOPE * v0);                \
      v1 = ry + dry; v1 = fmaxf(v1, SLOPE * v1);                \
      q = fmaf(v0, at.x, v1 * at.y);
      L2DOT(r0x, r0y, q0) L2DOT(r1x, r1y, q1) L2DOT(r2x, r2y, q2) L2DOT(r3x, r3y, q3)
#undef L2DOT
    }
    float p0, p1, p2, p3;
    packedReduce4(q0, q1, q2, q3, p0, p1, p2, p3);
    if (k0 + 1 >= end) p1 = -INFINITY;
    if (k0 + 2 >= end) p2 = -INFINITY;
    if (k0 + 3 >= end) p3 = -INFINITY;

    float mn = fmaxf(fmaxf(m, fmaxf(p0, p1)), fmaxf(p2, p3));
    float sc = __expf(m - mn);
    float w0 = __expf(p0 - mn), w1 = __expf(p1 - mn);
    float w2 = __expf(p2 - mn), w3 = __expf(p3 - mn);
    S  = fmaf(S, sc, (w0 + w1) + (w2 + w3));
    a0 = fmaf(a0, sc, fmaf(w0, r0x, fmaf(w1, r1x, fmaf(w2, r2x, w3 * r3x))));
    a1 = fmaf(a1, sc, fmaf(w0, r0y, fmaf(w1, r1y, fmaf(w2, r2y, w3 * r3y))));
    m = mn;
  }
  float inv = 1.f / S;
  float2 bz = *(const float2*)(bias2 + c0);
  float2 res;
  res.x = fmaf(a0, inv, bz.x);
  res.y = fmaf(a1, inv, bz.y);
  *(float2*)(out + (size_t)wid * 128 + c0) = res;
}

extern "C" void kernel_launch(void* const* d_in, const int* in_sizes, int n_in,
                              void* d_out, int out_size, void* d_ws, size_t ws_size,
                              hipStream_t stream) {
  const float* x      = (const float*)d_in[0];
  const int*   ei     = (const int*)d_in[1];
  const float* Wl1    = (const float*)d_in[2];
  const float* bl1    = (const float*)d_in[3];
  const float* Wr1    = (const float*)d_in[4];
  const float* br1    = (const float*)d_in[5];
  const float* att1   = (const float*)d_in[6];
  const float* bias1  = (const float*)d_in[7];
  const float* prelu  = (const float*)d_in[8];
  const float* Wl2    = (const float*)d_in[9];
  const float* bl2    = (const float*)d_in[10];
  const float* Wr2    = (const float*)d_in[11];
  const float* br2    = (const float*)d_in[12];
  const float* att2   = (const float*)d_in[13];
  const float* bias2  = (const float*)d_in[14];
  float* out = (float*)d_out;

  int N = in_sizes[0];       // x is [N,1]
  int E = in_sizes[1] / 2;   // edge_index [2,E]
  int Etot = E + N;          // + self loops

  char* ws = (char*)d_ws;
  size_t off = 0;
  auto alloc = [&](size_t bytes) -> void* {
    void* p = ws + off;
    off = (off + bytes + 255) & ~(size_t)255;
    return p;
  };
  float* S1     = (float*)alloc((size_t)N * 4);
  unsigned short* xl2b = (unsigned short*)alloc((size_t)N * 128 * 2);
  unsigned short* xr2b = (unsigned short*)alloc((size_t)N * 128 * 2);
  int*   deg    = (int*)alloc((size_t)N * 4);
  int*   cnt    = (int*)alloc((size_t)N * 4);
  int*   rowptr = (int*)alloc((size_t)(N + 1) * 4);
  int*   srcs   = (int*)alloc((size_t)Etot * 4);
  __hip_bfloat16* Wt = (__hip_bfloat16*)alloc((size_t)256 * 256 * 2);
  (void)ws_size; (void)n_in; (void)out_size;

  hipMemsetAsync(deg, 0, (size_t)N * 4, stream);
  hipMemsetAsync(cnt, 0, (size_t)N * 4, stream);

  int gE = (Etot + 255) / 256;
  count_kernel<<<gE, 256, 0, stream>>>(ei, E, N, deg);
  scan_kernel<<<1, 1024, 0, stream>>>(deg, N, rowptr);
  scatter_kernel<<<gE, 256, 0, stream>>>(ei, E, N, rowptr, cnt, srcs);

  wcvt_kernel<<<dim3(8, 8), 1024, 0, stream>>>(Wl2, Wr2, Wt);

  l1_fused_kernel<<<(N + 3) / 4, 256, 0, stream>>>(x, srcs, rowptr, N,
                                                   Wl1, bl1, Wr1, br1, att1, S1);
  l2_transform_mfma<<<(N + 127) / 128, 512, 0, stream>>>(S1, Wl1, bl1, bias1, prelu,
                                                         Wt, bl2, br2, N, xl2b, xr2b);
  l2_fused_kernel<<<(N + 3) / 4, 256, 0, stream>>>(xl2b, xr2b, srcs, rowptr,
                                                   att2, bias2, N, out);
}

// Round 5
// 311.836 us; speedup vs baseline: 2.8202x; 1.2219x over previous
//
#include <hip/hip_runtime.h>
#include <hip/hip_bf16.h>

#define SLOPE 0.2f

typedef __attribute__((ext_vector_type(8))) short short8;
typedef __attribute__((ext_vector_type(4))) float f32x4;

static __device__ __forceinline__ float bf2f(unsigned short u) {
  unsigned int x = ((unsigned int)u) << 16;
  return __uint_as_float(x);
}
static __device__ __forceinline__ unsigned short f2bf(float f) {
  __hip_bfloat16 h = __float2bfloat16(f);
  return *reinterpret_cast<unsigned short*>(&h);
}

// Packed 4-value wave reduce: lanes hold partials q0..q3 (one per edge).
// Returns p0..p3 = full 64-lane sums, broadcast to all lanes.
static __device__ __forceinline__ void packedReduce4(
    float q0, float q1, float q2, float q3,
    float& p0, float& p1, float& p2, float& p3) {
  int lane = threadIdx.x & 63;
  float u = (lane & 1) ? q1 : q0;   // keep
  float v = (lane & 1) ? q0 : q1;   // give
  u += __shfl_xor(v, 1, 64);
  float w = (lane & 1) ? q3 : q2;
  float z = (lane & 1) ? q2 : q3;
  w += __shfl_xor(z, 1, 64);
  float a = (lane & 2) ? w : u;     // keep
  float b = (lane & 2) ? u : w;     // give
  a += __shfl_xor(b, 2, 64);
  a += __shfl_xor(a, 4, 64);
  a += __shfl_xor(a, 8, 64);
  a += __shfl_xor(a, 16, 64);
  a += __shfl_xor(a, 32, 64);
  p0 = __shfl(a, 0, 64);
  p1 = __shfl(a, 1, 64);
  p2 = __shfl(a, 2, 64);
  p3 = __shfl(a, 3, 64);
}

// ---------- CSR build ----------
__global__ void count_kernel(const int* __restrict__ ei, int E, int N, int* __restrict__ deg) {
  int j = blockIdx.x * blockDim.x + threadIdx.x;
  int Etot = E + N;
  if (j >= Etot) return;
  int d = (j < E) ? ei[E + j] : (j - E);
  atomicAdd(&deg[d], 1);
}

// Parallel scan phase 1: per-block sums (1024 elems/block)
__global__ __launch_bounds__(1024) void scan1_kernel(const int* __restrict__ deg, int N,
                                                     int* __restrict__ bsum) {
  __shared__ int ws[16];
  int i = blockIdx.x * 1024 + threadIdx.x;
  int v = (i < N) ? deg[i] : 0;
#pragma unroll
  for (int off = 32; off > 0; off >>= 1) v += __shfl_xor(v, off, 64);
  int wave = threadIdx.x >> 6;
  if ((threadIdx.x & 63) == 0) ws[wave] = v;
  __syncthreads();
  if (threadIdx.x == 0) {
    int s = 0;
#pragma unroll
    for (int k = 0; k < 16; ++k) s += ws[k];
    bsum[blockIdx.x] = s;
  }
}

// Parallel scan phase 2: exclusive scan of block sums (B <= 1024)
__global__ __launch_bounds__(1024) void scan2_kernel(const int* __restrict__ bsum, int B,
                                                     int* __restrict__ boff) {
  __shared__ int s[1024];
  int tid = threadIdx.x;
  s[tid] = (tid < B) ? bsum[tid] : 0;
  __syncthreads();
  for (int off = 1; off < 1024; off <<= 1) {
    int t = (tid >= off) ? s[tid - off] : 0;
    __syncthreads();
    s[tid] += t;
    __syncthreads();
  }
  if (tid < B) boff[tid] = (tid == 0) ? 0 : s[tid - 1];
}

// Parallel scan phase 3: block-local scan + offset -> rowptr (exclusive)
__global__ __launch_bounds__(1024) void scan3_kernel(const int* __restrict__ deg,
                                                     const int* __restrict__ boff, int N,
                                                     int* __restrict__ rowptr) {
  __shared__ int s[1024];
  int tid = threadIdx.x;
  int i = blockIdx.x * 1024 + tid;
  int v = (i < N) ? deg[i] : 0;
  s[tid] = v;
  __syncthreads();
  for (int off = 1; off < 1024; off <<= 1) {
    int t = (tid >= off) ? s[tid - off] : 0;
    __syncthreads();
    s[tid] += t;
    __syncthreads();
  }
  int base = boff[blockIdx.x];
  if (i < N) {
    rowptr[i] = base + s[tid] - v;       // exclusive
    if (i == N - 1) rowptr[N] = base + s[tid];
  }
}

// Scatter: consume deg via atomicSub (deg dead after scan; segment order free)
__global__ void scatter_kernel(const int* __restrict__ ei, int E, int N,
                               const int* __restrict__ rowptr, int* __restrict__ deg,
                               int* __restrict__ srcs) {
  int j = blockIdx.x * blockDim.x + threadIdx.x;
  int Etot = E + N;
  if (j >= Etot) return;
  int s, d;
  if (j < E) { s = ei[j]; d = ei[E + j]; } else { s = j - E; d = j - E; }
  int pos = rowptr[d] + (atomicSub(&deg[d], 1) - 1);
  srcs[pos] = s;
}

// ---------- Layer 1 fused: online softmax + scalar aggregation -> S1 ----------
__global__ __launch_bounds__(256) void l1_fused_kernel(
    const float* __restrict__ x, const int* __restrict__ srcs,
    const int* __restrict__ rowptr, int N,
    const float* __restrict__ Wl1, const float* __restrict__ bl1,
    const float* __restrict__ Wr1, const float* __restrict__ br1,
    const float* __restrict__ att1, float* __restrict__ S1) {
  int wid = (blockIdx.x * blockDim.x + threadIdx.x) >> 6;
  int lane = threadIdx.x & 63;
  if (wid >= N) return;
  int c0 = lane * 4;
  float4 wl = *(const float4*)(Wl1 + c0);
  float4 wr = *(const float4*)(Wr1 + c0);
  float4 ba = *(const float4*)(bl1 + c0);
  float4 bb = *(const float4*)(br1 + c0);
  float4 at = *(const float4*)(att1 + c0);
  float xd = x[wid];
  float cc0 = fmaf(xd, wr.x, ba.x + bb.x);
  float cc1 = fmaf(xd, wr.y, ba.y + bb.y);
  float cc2 = fmaf(xd, wr.z, ba.z + bb.z);
  float cc3 = fmaf(xd, wr.w, ba.w + bb.w);

  int base = rowptr[wid], end = rowptr[wid + 1];
  float m = -INFINITY, S = 0.f, vs = 0.f;
  for (int k0 = base; k0 < end; k0 += 4) {
    int k1 = min(k0 + 1, end - 1);
    int k2 = min(k0 + 2, end - 1);
    int k3 = min(k0 + 3, end - 1);
    float xs0 = x[srcs[k0]];
    float xs1 = x[srcs[k1]];
    float xs2 = x[srcs[k2]];
    float xs3 = x[srcs[k3]];

    float q0, q1, q2, q3;
    {
      float t0, t1, t2, t3;
#define L1DOT(xs, q)                                              \
      t0 = fmaf(xs, wl.x, cc0); t0 = fmaxf(t0, SLOPE * t0);       \
      t1 = fmaf(xs, wl.y, cc1); t1 = fmaxf(t1, SLOPE * t1);       \
      t2 = fmaf(xs, wl.z, cc2); t2 = fmaxf(t2, SLOPE * t2);       \
      t3 = fmaf(xs, wl.w, cc3); t3 = fmaxf(t3, SLOPE * t3);       \
      q = fmaf(t0, at.x, fmaf(t1, at.y, fmaf(t2, at.z, t3 * at.w)));
      L1DOT(xs0, q0) L1DOT(xs1, q1) L1DOT(xs2, q2) L1DOT(xs3, q3)
#undef L1DOT
    }
    float p0, p1, p2, p3;
    packedReduce4(q0, q1, q2, q3, p0, p1, p2, p3);
    if (k0 + 1 >= end) p1 = -INFINITY;
    if (k0 + 2 >= end) p2 = -INFINITY;
    if (k0 + 3 >= end) p3 = -INFINITY;

    float mn = fmaxf(fmaxf(m, fmaxf(p0, p1)), fmaxf(p2, p3));
    float sc = __expf(m - mn);
    float w0 = __expf(p0 - mn), w1 = __expf(p1 - mn);
    float w2 = __expf(p2 - mn), w3 = __expf(p3 - mn);
    S  = fmaf(S, sc, (w0 + w1) + (w2 + w3));
    vs = fmaf(vs, sc, fmaf(w0, xs0, fmaf(w1, xs1, fmaf(w2, xs2, w3 * xs3))));
    m = mn;
  }
  if (lane == 0) S1[wid] = vs / S;
}

// ---------- Weight prep: Wt[c][k] = bf16(Wcat[k][c]), c<128 -> Wl2, else Wr2 ----------
__global__ __launch_bounds__(1024) void wcvt_kernel(
    const float* __restrict__ Wl2, const float* __restrict__ Wr2,
    __hip_bfloat16* __restrict__ Wt) {
  __shared__ float tile[32][33];
  int k0 = blockIdx.y * 32, c0 = blockIdx.x * 32;
  int tx = threadIdx.x & 31, ty = threadIdx.x >> 5;
  int k = k0 + ty, c = c0 + tx;
  float v = (c < 128) ? Wl2[(size_t)k * 128 + c] : Wr2[(size_t)k * 128 + (c - 128)];
  tile[ty][tx] = v;
  __syncthreads();
  Wt[(size_t)(c0 + ty) * 256 + k0 + tx] = __float2bfloat16(tile[tx][ty]);
}

// ---------- Layer 2 transform via MFMA -> bf16 xl2/xr2 ----------
__global__ __launch_bounds__(512) void l2_transform_mfma(
    const float* __restrict__ S1,
    const float* __restrict__ Wl1, const float* __restrict__ bl1,
    const float* __restrict__ bias1, const float* __restrict__ prelu_w,
    const __hip_bfloat16* __restrict__ Wt,
    const float* __restrict__ bl2, const float* __restrict__ br2,
    int N, unsigned short* __restrict__ xl2b, unsigned short* __restrict__ xr2b) {
  int w = threadIdx.x >> 6;
  int lane = threadIdx.x & 63;
  int l15 = lane & 15, lk = lane >> 4;
  int rbase = blockIdx.x * 128 + (w & 1) * 64;
  int cbase = (w >> 1) * 64;

  float s1v[4];
#pragma unroll
  for (int mt = 0; mt < 4; ++mt) {
    int r = rbase + mt * 16 + l15;
    s1v[mt] = (r < N) ? S1[r] : 0.f;
  }

  f32x4 acc[4][4] = {};

#pragma unroll
  for (int ks = 0; ks < 8; ++ks) {
    int k0 = ks * 32 + lk * 8;
    float4 wl1a = *(const float4*)(Wl1 + k0);
    float4 wl1b = *(const float4*)(Wl1 + k0 + 4);
    float4 b1a  = *(const float4*)(bl1 + k0);
    float4 b1b  = *(const float4*)(bl1 + k0 + 4);
    float4 z1a  = *(const float4*)(bias1 + k0);
    float4 z1b  = *(const float4*)(bias1 + k0 + 4);
    float4 pwa  = *(const float4*)(prelu_w + k0);
    float4 pwb  = *(const float4*)(prelu_w + k0 + 4);
    float wv[8] = {wl1a.x, wl1a.y, wl1a.z, wl1a.w, wl1b.x, wl1b.y, wl1b.z, wl1b.w};
    float cv[8] = {b1a.x + z1a.x, b1a.y + z1a.y, b1a.z + z1a.z, b1a.w + z1a.w,
                   b1b.x + z1b.x, b1b.y + z1b.y, b1b.z + z1b.z, b1b.w + z1b.w};
    float pv[8] = {pwa.x, pwa.y, pwa.z, pwa.w, pwb.x, pwb.y, pwb.z, pwb.w};

    short8 afrag[4];
#pragma unroll
    for (int mt = 0; mt < 4; ++mt) {
      short8 a;
#pragma unroll
      for (int j = 0; j < 8; ++j) {
        float t = fmaf(wv[j], s1v[mt], cv[j]);
        t = (t > 0.f) ? t : pv[j] * t;
        a[j] = (short)f2bf(t);
      }
      afrag[mt] = a;
    }

    short8 bfrag[4];
#pragma unroll
    for (int nt = 0; nt < 4; ++nt) {
      int col = cbase + nt * 16 + l15;
      bfrag[nt] = *(const short8*)(Wt + (size_t)col * 256 + k0);
    }

#pragma unroll
    for (int mt = 0; mt < 4; ++mt)
#pragma unroll
      for (int nt = 0; nt < 4; ++nt)
        acc[mt][nt] = __builtin_amdgcn_mfma_f32_16x16x32_bf16(afrag[mt], bfrag[nt],
                                                              acc[mt][nt], 0, 0, 0);
  }

#pragma unroll
  for (int mt = 0; mt < 4; ++mt) {
#pragma unroll
    for (int nt = 0; nt < 4; ++nt) {
      int col = cbase + nt * 16 + l15;
      float bias;
      unsigned short* dst;
      int cc;
      if (col < 128) { bias = bl2[col]; dst = xl2b; cc = col; }
      else           { bias = br2[col - 128]; dst = xr2b; cc = col - 128; }
#pragma unroll
      for (int r = 0; r < 4; ++r) {
        int row = rbase + mt * 16 + lk * 4 + r;
        if (row < N) dst[(size_t)row * 128 + cc] = f2bf(acc[mt][nt][r] + bias);
      }
    }
  }
}

// ---------- Layer 2 fused: online softmax + row aggregation -> out ----------
__global__ __launch_bounds__(256) void l2_fused_kernel(
    const unsigned short* __restrict__ xl2b, const unsigned short* __restrict__ xr2b,
    const int* __restrict__ srcs, const int* __restrict__ rowptr,
    const float* __restrict__ att2, const float* __restrict__ bias2,
    int N, float* __restrict__ out) {
  int wid = (blockIdx.x * blockDim.x + threadIdx.x) >> 6;
  int lane = threadIdx.x & 63;
  if (wid >= N) return;
  int c0 = lane * 2;
  float2 at = *(const float2*)(att2 + c0);
  ushort2 dru = *(const ushort2*)(xr2b + (size_t)wid * 128 + c0);
  float drx = bf2f(dru.x), dry = bf2f(dru.y);
  int base = rowptr[wid], end = rowptr[wid + 1];
  float m = -INFINITY, S = 0.f, a0 = 0.f, a1 = 0.f;
  for (int k0 = base; k0 < end; k0 += 4) {
    int k1 = min(k0 + 1, end - 1);
    int k2 = min(k0 + 2, end - 1);
    int k3 = min(k0 + 3, end - 1);
    int s0 = srcs[k0], s1 = srcs[k1], s2 = srcs[k2], s3 = srcs[k3];
    ushort2 u0 = *(const ushort2*)(xl2b + (size_t)s0 * 128 + c0);
    ushort2 u1 = *(const ushort2*)(xl2b + (size_t)s1 * 128 + c0);
    ushort2 u2 = *(const ushort2*)(xl2b + (size_t)s2 * 128 + c0);
    ushort2 u3 = *(const ushort2*)(xl2b + (size_t)s3 * 128 + c0);
    float r0x = bf2f(u0.x), r0y = bf2f(u0.y);
    float r1x = bf2f(u1.x), r1y = bf2f(u1.y);
    float r2x = bf2f(u2.x), r2y = bf2f(u2.y);
    float r3x = bf2f(u3.x), r3y = bf2f(u3.y);

    float q0, q1, q2, q3;
    {
      float v0, v1;
#define L2DOT(rx, ry, q)                                        \
      v0 = rx + drx; v0 = fmaxf(v0, SLOPE * v0);                \
      v1 = ry + dry; v1 = fmaxf(v1, SLOPE * v1);                \
      q = fmaf(v0, at.x, v1 * at.y);
      L2DOT(r0x, r0y, q0) L2DOT(r1x, r1y, q1) L2DOT(r2x, r2y, q2) L2DOT(r3x, r3y, q3)
#undef L2DOT
    }
    float p0, p1, p2, p3;
    packedReduce4(q0, q1, q2, q3, p0, p1, p2, p3);
    if (k0 + 1 >= end) p1 = -INFINITY;
    if (k0 + 2 >= end) p2 = -INFINITY;
    if (k0 + 3 >= end) p3 = -INFINITY;

    float mn = fmaxf(fmaxf(m, fmaxf(p0, p1)), fmaxf(p2, p3));
    float sc = __expf(m - mn);
    float w0 = __expf(p0 - mn), w1 = __expf(p1 - mn);
    float w2 = __expf(p2 - mn), w3 = __expf(p3 - mn);
    S  = fmaf(S, sc, (w0 + w1) + (w2 + w3));
    a0 = fmaf(a0, sc, fmaf(w0, r0x, fmaf(w1, r1x, fmaf(w2, r2x, w3 * r3x))));
    a1 = fmaf(a1, sc, fmaf(w0, r0y, fmaf(w1, r1y, fmaf(w2, r2y, w3 * r3y))));
    m = mn;
  }
  float inv = 1.f / S;
  float2 bz = *(const float2*)(bias2 + c0);
  float2 res;
  res.x = fmaf(a0, inv, bz.x);
  res.y = fmaf(a1, inv, bz.y);
  *(float2*)(out + (size_t)wid * 128 + c0) = res;
}

extern "C" void kernel_launch(void* const* d_in, const int* in_sizes, int n_in,
                              void* d_out, int out_size, void* d_ws, size_t ws_size,
                              hipStream_t stream) {
  const float* x      = (const float*)d_in[0];
  const int*   ei     = (const int*)d_in[1];
  const float* Wl1    = (const float*)d_in[2];
  const float* bl1    = (const float*)d_in[3];
  const float* Wr1    = (const float*)d_in[4];
  const float* br1    = (const float*)d_in[5];
  const float* att1   = (const float*)d_in[6];
  const float* bias1  = (const float*)d_in[7];
  const float* prelu  = (const float*)d_in[8];
  const float* Wl2    = (const float*)d_in[9];
  const float* bl2    = (const float*)d_in[10];
  const float* Wr2    = (const float*)d_in[11];
  const float* br2    = (const float*)d_in[12];
  const float* att2   = (const float*)d_in[13];
  const float* bias2  = (const float*)d_in[14];
  float* out = (float*)d_out;

  int N = in_sizes[0];       // x is [N,1]
  int E = in_sizes[1] / 2;   // edge_index [2,E]
  int Etot = E + N;          // + self loops

  char* ws = (char*)d_ws;
  size_t off = 0;
  auto alloc = [&](size_t bytes) -> void* {
    void* p = ws + off;
    off = (off + bytes + 255) & ~(size_t)255;
    return p;
  };
  float* S1     = (float*)alloc((size_t)N * 4);
  unsigned short* xl2b = (unsigned short*)alloc((size_t)N * 128 * 2);
  unsigned short* xr2b = (unsigned short*)alloc((size_t)N * 128 * 2);
  int*   deg    = (int*)alloc((size_t)N * 4);
  int*   rowptr = (int*)alloc((size_t)(N + 1) * 4);
  int*   srcs   = (int*)alloc((size_t)Etot * 4);
  int*   bsum   = (int*)alloc((size_t)1024 * 4);
  int*   boff   = (int*)alloc((size_t)1024 * 4);
  __hip_bfloat16* Wt = (__hip_bfloat16*)alloc((size_t)256 * 256 * 2);
  (void)ws_size; (void)n_in; (void)out_size;

  hipMemsetAsync(deg, 0, (size_t)N * 4, stream);

  int gE = (Etot + 255) / 256;
  int B = (N + 1023) / 1024;
  count_kernel<<<gE, 256, 0, stream>>>(ei, E, N, deg);
  scan1_kernel<<<B, 1024, 0, stream>>>(deg, N, bsum);
  scan2_kernel<<<1, 1024, 0, stream>>>(bsum, B, boff);
  scan3_kernel<<<B, 1024, 0, stream>>>(deg, boff, N, rowptr);
  scatter_kernel<<<gE, 256, 0, stream>>>(ei, E, N, rowptr, deg, srcs);

  wcvt_kernel<<<dim3(8, 8), 1024, 0, stream>>>(Wl2, Wr2, Wt);

  l1_fused_kernel<<<(N + 3) / 4, 256, 0, stream>>>(x, srcs, rowptr, N,
                                                   Wl1, bl1, Wr1, br1, att1, S1);
  l2_transform_mfma<<<(N + 127) / 128, 512, 0, stream>>>(S1, Wl1, bl1, bias1, prelu,
                                                         Wt, bl2, br2, N, xl2b, xr2b);
  l2_fused_kernel<<<(N + 3) / 4, 256, 0, stream>>>(xl2b, xr2b, srcs, rowptr,
                                                   att2, bias2, N, out);
}